// Round 3
// baseline (364.141 us; speedup 1.0000x reference)
//
#include <hip/hip_runtime.h>
#include <hip/hip_bf16.h>
#include <math.h>

#define NHEADS 16
#define DKH 64
#define SEQ 2048
#define DMODEL 1024

typedef __attribute__((ext_vector_type(8))) short short8;
typedef __attribute__((ext_vector_type(4))) float f32x4;

__device__ __forceinline__ short f2bf(float f) {
  unsigned u = __float_as_uint(f);
  unsigned r = (u + 0x7fffu + ((u >> 16) & 1u)) >> 16;
  return (short)r;
}

__device__ __forceinline__ short8 pack8(float4 a, float4 b) {
  short8 v;
  v[0] = f2bf(a.x); v[1] = f2bf(a.y); v[2] = f2bf(a.z); v[3] = f2bf(a.w);
  v[4] = f2bf(b.x); v[5] = f2bf(b.y); v[6] = f2bf(b.z); v[7] = f2bf(b.w);
  return v;
}

// Swizzled LDS tile [rows][64] bf16. Granule = 8 elems (16B).
// Element (r,c) lives at short index r*64 + (((c>>3) ^ (r&7))<<3) + (c&7).
__device__ __forceinline__ int swz(int r, int gran) {
  return r * 64 + ((gran ^ (r & 7)) << 3);
}

// ---------------- RoPE cos/sin table ----------------
__global__ void rope_table_kernel(const int* __restrict__ tp,
                                  float* __restrict__ ct, float* __restrict__ st) {
  int idx = blockIdx.x * 256 + threadIdx.x;
  if (idx >= SEQ * 32) return;
  int s = idx >> 5, i = idx & 31;
  // robust to int32 vs int64 storage of arange(SEQ): int64 LE -> words [0,0,1,0,2,0,...]
  int is64 = (tp[1] == 0);
  int p = is64 ? tp[2 * s] : tp[s];
  float invf = powf(10000.0f, -(2.0f * (float)i) / 64.0f);
  float a = (float)p * invf;
  ct[idx] = cosf(a);
  st[idx] = sinf(a);
}

// ---------------- fused QKV projection + RoPE ----------------
// C[r][n] = sum_d X[r][d] * W[n][d];  X: 4096x1024 fp32, W: 3x(1024x1024) fp32
__global__ __launch_bounds__(256) void gemm_qkv_kernel(
    const float* __restrict__ X, const float* __restrict__ Wq,
    const float* __restrict__ Wk, const float* __restrict__ Wv,
    short* __restrict__ Qb, short* __restrict__ Kb, short* __restrict__ Vb,
    const float* __restrict__ ct, const float* __restrict__ st) {
  __shared__ __align__(16) short As[64 * 64];
  __shared__ __align__(16) short Bs[64 * 64];
  const int tm = blockIdx.x;          // 64 row tiles
  const int tn = blockIdx.y;          // 48 col tiles (3*1024/64)
  const int tid = threadIdx.x;
  const int wave = tid >> 6, lane = tid & 63;
  const int l15 = lane & 15, quad = lane >> 4;

  const int mid = (tn * 64) >> 10;     // 0=Q 1=K 2=V
  const int n0 = (tn * 64) & 1023;
  const float* W = (mid == 0) ? Wq : (mid == 1 ? Wk : Wv);
  const float* Arow = X + (size_t)(tm * 64) * DMODEL;
  const float* Wrow = W + (size_t)n0 * DMODEL;

  f32x4 acc[4];
#pragma unroll
  for (int i = 0; i < 4; i++) acc[i] = (f32x4){0.f, 0.f, 0.f, 0.f};

  for (int kk = 0; kk < DMODEL; kk += 64) {
#pragma unroll
    for (int i = 0; i < 2; i++) {
      int g = tid + i * 256;
      int r = g >> 3, c = g & 7;
      const float* ap = Arow + (size_t)r * DMODEL + kk + c * 8;
      float4 a0 = *reinterpret_cast<const float4*>(ap);
      float4 a1 = *reinterpret_cast<const float4*>(ap + 4);
      *reinterpret_cast<short8*>(&As[swz(r, c)]) = pack8(a0, a1);
      const float* bp = Wrow + (size_t)r * DMODEL + kk + c * 8;
      float4 b0 = *reinterpret_cast<const float4*>(bp);
      float4 b1 = *reinterpret_cast<const float4*>(bp + 4);
      *reinterpret_cast<short8*>(&Bs[swz(r, c)]) = pack8(b0, b1);
    }
    __syncthreads();
    short8 af0, af1;
    {
      int r = wave * 16 + l15;
      af0 = *reinterpret_cast<const short8*>(&As[swz(r, quad)]);
      af1 = *reinterpret_cast<const short8*>(&As[swz(r, 4 + quad)]);
    }
#pragma unroll
    for (int nb = 0; nb < 4; nb++) {
      int r = nb * 16 + l15;
      short8 bf0 = *reinterpret_cast<const short8*>(&Bs[swz(r, quad)]);
      acc[nb] = __builtin_amdgcn_mfma_f32_16x16x32_bf16(af0, bf0, acc[nb], 0, 0, 0);
      short8 bf1 = *reinterpret_cast<const short8*>(&Bs[swz(r, 4 + quad)]);
      acc[nb] = __builtin_amdgcn_mfma_f32_16x16x32_bf16(af1, bf1, acc[nb], 0, 0, 0);
    }
    __syncthreads();
  }
  // epilogue: scatter into (B,H,S,64); RoPE for Q,K via lane-pair shuffle
#pragma unroll
  for (int nb = 0; nb < 4; nb++) {
    int nl = n0 + nb * 16 + l15;       // feature within this matrix, 0..1023
    int h = nl >> 6, dd = nl & 63;
#pragma unroll
    for (int reg = 0; reg < 4; reg++) {
      int rg = tm * 64 + wave * 16 + quad * 4 + reg;   // global row, 0..4095
      int b = rg >> 11, s = rg & 2047;
      float v = acc[nb][reg];
      size_t oi = (((size_t)(b * NHEADS + h)) * SEQ + s) * DKH + dd;
      if (mid == 2) {
        Vb[oi] = f2bf(v);
      } else {
        float pv = __shfl_xor(v, 1);
        int fi = dd >> 1;
        float c = ct[s * 32 + fi], sn = st[s * 32 + fi];
        float o = (dd & 1) ? (pv * sn + v * c) : (v * c - pv * sn);
        ((mid == 0) ? Qb : Kb)[oi] = f2bf(o);
      }
    }
  }
}

// ---------------- flash attention (causal) ----------------
__global__ __launch_bounds__(256) void attn_kernel(
    const short* __restrict__ Qb, const short* __restrict__ Kb,
    const short* __restrict__ Vb, short* __restrict__ Ob) {
  __shared__ __align__(16) short Qs[64 * 64];
  __shared__ __align__(16) short Ks[64 * 64];
  __shared__ __align__(16) short Vs[64 * 64];       // transposed: [dv][key]
  __shared__ __align__(16) short Ps[4][16 * 64];    // per-wave P tile

  const int qt = blockIdx.x;   // 0..31 query tile
  const int bh = blockIdx.y;   // 0..31 (b*16+h)
  const int tid = threadIdx.x;
  const int wave = tid >> 6, lane = tid & 63;
  const int l15 = lane & 15, quad = lane >> 4;

  const short* Qp = Qb + (size_t)bh * SEQ * DKH;
  const short* Kp = Kb + (size_t)bh * SEQ * DKH;
  const short* Vp = Vb + (size_t)bh * SEQ * DKH;

#pragma unroll
  for (int i = 0; i < 2; i++) {
    int g = tid + i * 256;
    int r = g >> 3, c = g & 7;
    uint4 v = *reinterpret_cast<const uint4*>(Qp + (size_t)(qt * 64 + r) * DKH + c * 8);
    *reinterpret_cast<uint4*>(&Qs[swz(r, c)]) = v;
  }
  __syncthreads();
  short8 qf0, qf1;
  {
    int r = wave * 16 + l15;
    qf0 = *reinterpret_cast<const short8*>(&Qs[swz(r, quad)]);
    qf1 = *reinterpret_cast<const short8*>(&Qs[swz(r, 4 + quad)]);
  }

  f32x4 accO[4];
#pragma unroll
  for (int i = 0; i < 4; i++) accO[i] = (f32x4){0.f, 0.f, 0.f, 0.f};
  float mrow[4] = {-1e30f, -1e30f, -1e30f, -1e30f};
  float lrow[4] = {0.f, 0.f, 0.f, 0.f};

  for (int kt = 0; kt <= qt; kt++) {
    __syncthreads();   // previous iteration's readers done before restaging
#pragma unroll
    for (int i = 0; i < 2; i++) {
      int g = tid + i * 256;
      int r = g >> 3, c = g & 7;
      uint4 kv = *reinterpret_cast<const uint4*>(Kp + (size_t)(kt * 64 + r) * DKH + c * 8);
      *reinterpret_cast<uint4*>(&Ks[swz(r, c)]) = kv;
      uint4 vv = *reinterpret_cast<const uint4*>(Vp + (size_t)(kt * 64 + r) * DKH + c * 8);
      const short* vs = reinterpret_cast<const short*>(&vv);
#pragma unroll
      for (int j = 0; j < 8; j++) {
        int dv = c * 8 + j;
        Vs[dv * 64 + (((r >> 3) ^ (dv & 7)) << 3) + (r & 7)] = vs[j];
      }
    }
    __syncthreads();

    // S = Q K^T / 8, causal mask on diagonal tile
    f32x4 sa[4];
#pragma unroll
    for (int nb = 0; nb < 4; nb++) {
      sa[nb] = (f32x4){0.f, 0.f, 0.f, 0.f};
      int r = nb * 16 + l15;
      short8 kf0 = *reinterpret_cast<const short8*>(&Ks[swz(r, quad)]);
      sa[nb] = __builtin_amdgcn_mfma_f32_16x16x32_bf16(qf0, kf0, sa[nb], 0, 0, 0);
      short8 kf1 = *reinterpret_cast<const short8*>(&Ks[swz(r, 4 + quad)]);
      sa[nb] = __builtin_amdgcn_mfma_f32_16x16x32_bf16(qf1, kf1, sa[nb], 0, 0, 0);
    }
    float sv[4][4];
#pragma unroll
    for (int nb = 0; nb < 4; nb++)
#pragma unroll
      for (int reg = 0; reg < 4; reg++) {
        float x = sa[nb][reg] * 0.125f;
        if (kt == qt && (nb * 16 + l15) > (wave * 16 + quad * 4 + reg)) x = -1e30f;
        sv[nb][reg] = x;
      }
    // online softmax state per row (row = quad*4+reg; 16 lanes of quad = 16 cols)
    float mnew[4], alpha[4];
#pragma unroll
    for (int reg = 0; reg < 4; reg++) {
      float rm = fmaxf(fmaxf(sv[0][reg], sv[1][reg]), fmaxf(sv[2][reg], sv[3][reg]));
#pragma unroll
      for (int off = 1; off < 16; off <<= 1) rm = fmaxf(rm, __shfl_xor(rm, off));
      mnew[reg] = fmaxf(mrow[reg], rm);
      alpha[reg] = __expf(mrow[reg] - mnew[reg]);
      mrow[reg] = mnew[reg];
    }
    float rs[4] = {0.f, 0.f, 0.f, 0.f};
#pragma unroll
    for (int nb = 0; nb < 4; nb++)
#pragma unroll
      for (int reg = 0; reg < 4; reg++) {
        float p = __expf(sv[nb][reg] - mnew[reg]);
        rs[reg] += p;
        int r = quad * 4 + reg, col = nb * 16 + l15;
        Ps[wave][r * 64 + (((col >> 3) ^ (r & 7)) << 3) + (col & 7)] = f2bf(p);
      }
#pragma unroll
    for (int reg = 0; reg < 4; reg++) {
      float t = rs[reg];
#pragma unroll
      for (int off = 1; off < 16; off <<= 1) t += __shfl_xor(t, off);
      lrow[reg] = lrow[reg] * alpha[reg] + t;
    }
#pragma unroll
    for (int db = 0; db < 4; db++)
#pragma unroll
      for (int reg = 0; reg < 4; reg++) accO[db][reg] *= alpha[reg];
    __syncthreads();   // P LDS write -> read

    // O += P V   (P in A-layout from LDS, V transposed in LDS)
    short8 pf0, pf1;
    {
      int r = l15;
      pf0 = *reinterpret_cast<const short8*>(&Ps[wave][swz(r, quad)]);
      pf1 = *reinterpret_cast<const short8*>(&Ps[wave][swz(r, 4 + quad)]);
    }
#pragma unroll
    for (int db = 0; db < 4; db++) {
      int r = db * 16 + l15;
      short8 vf0 = *reinterpret_cast<const short8*>(&Vs[swz(r, quad)]);
      accO[db] = __builtin_amdgcn_mfma_f32_16x16x32_bf16(pf0, vf0, accO[db], 0, 0, 0);
      short8 vf1 = *reinterpret_cast<const short8*>(&Vs[swz(r, 4 + quad)]);
      accO[db] = __builtin_amdgcn_mfma_f32_16x16x32_bf16(pf1, vf1, accO[db], 0, 0, 0);
    }
  }

  // write (B,S,1024) bf16
  int b = bh >> 4, h = bh & 15;
#pragma unroll
  for (int db = 0; db < 4; db++)
#pragma unroll
    for (int reg = 0; reg < 4; reg++) {
      int s = qt * 64 + wave * 16 + quad * 4 + reg;
      int dv = db * 16 + l15;
      float o = accO[db][reg] / lrow[reg];
      Ob[((size_t)(b * SEQ + s)) * DMODEL + h * DKH + dv] = f2bf(o);
    }
}

// ---------------- output projection (fp32 output) ----------------
__global__ __launch_bounds__(256) void gemm_out_kernel(
    const short* __restrict__ X, const float* __restrict__ Wo, float* __restrict__ Out) {
  __shared__ __align__(16) short As[64 * 64];
  __shared__ __align__(16) short Bs[64 * 64];
  const int tm = blockIdx.x;   // 64
  const int tn = blockIdx.y;   // 16
  const int tid = threadIdx.x;
  const int wave = tid >> 6, lane = tid & 63;
  const int l15 = lane & 15, quad = lane >> 4;

  const short* Arow = X + (size_t)(tm * 64) * DMODEL;
  const float* Wrow = Wo + (size_t)(tn * 64) * DMODEL;

  f32x4 acc[4];
#pragma unroll
  for (int i = 0; i < 4; i++) acc[i] = (f32x4){0.f, 0.f, 0.f, 0.f};

  for (int kk = 0; kk < DMODEL; kk += 64) {
#pragma unroll
    for (int i = 0; i < 2; i++) {
      int g = tid + i * 256;
      int r = g >> 3, c = g & 7;
      uint4 va = *reinterpret_cast<const uint4*>(Arow + (size_t)r * DMODEL + kk + c * 8);
      *reinterpret_cast<uint4*>(&As[swz(r, c)]) = va;
      const float* bp = Wrow + (size_t)r * DMODEL + kk + c * 8;
      float4 b0 = *reinterpret_cast<const float4*>(bp);
      float4 b1 = *reinterpret_cast<const float4*>(bp + 4);
      *reinterpret_cast<short8*>(&Bs[swz(r, c)]) = pack8(b0, b1);
    }
    __syncthreads();
    short8 af0, af1;
    {
      int r = wave * 16 + l15;
      af0 = *reinterpret_cast<const short8*>(&As[swz(r, quad)]);
      af1 = *reinterpret_cast<const short8*>(&As[swz(r, 4 + quad)]);
    }
#pragma unroll
    for (int nb = 0; nb < 4; nb++) {
      int r = nb * 16 + l15;
      short8 bf0 = *reinterpret_cast<const short8*>(&Bs[swz(r, quad)]);
      acc[nb] = __builtin_amdgcn_mfma_f32_16x16x32_bf16(af0, bf0, acc[nb], 0, 0, 0);
      short8 bf1 = *reinterpret_cast<const short8*>(&Bs[swz(r, 4 + quad)]);
      acc[nb] = __builtin_amdgcn_mfma_f32_16x16x32_bf16(af1, bf1, acc[nb], 0, 0, 0);
    }
    __syncthreads();
  }
#pragma unroll
  for (int nb = 0; nb < 4; nb++)
#pragma unroll
    for (int reg = 0; reg < 4; reg++) {
      int rg = tm * 64 + wave * 16 + quad * 4 + reg;
      int col = tn * 64 + nb * 16 + l15;
      Out[(size_t)rg * DMODEL + col] = acc[nb][reg];
    }
}

extern "C" void kernel_launch(void* const* d_in, const int* in_sizes, int n_in,
                              void* d_out, int out_size, void* d_ws, size_t ws_size,
                              hipStream_t stream) {
  (void)in_sizes; (void)n_in; (void)out_size; (void)ws_size;
  const float* X  = (const float*)d_in[0];
  const int*   tp = (const int*)d_in[1];
  const float* Wq = (const float*)d_in[2];
  const float* Wk = (const float*)d_in[3];
  const float* Wv = (const float*)d_in[4];
  const float* Wo = (const float*)d_in[5];
  float* Out = (float*)d_out;

  short* Qb = (short*)d_ws;            // 4194304 bf16 each
  short* Kb = Qb + 4194304;
  short* Vb = Kb + 4194304;
  short* Ab = Vb + 4194304;
  float* ct = (float*)(Ab + 4194304);  // 65536 floats
  float* st = ct + SEQ * 32;

  rope_table_kernel<<<dim3(256), dim3(256), 0, stream>>>(tp, ct, st);
  gemm_qkv_kernel<<<dim3(64, 48), dim3(256), 0, stream>>>(X, Wq, Wk, Wv, Qb, Kb, Vb, ct, st);
  attn_kernel<<<dim3(32, 32), dim3(256), 0, stream>>>(Qb, Kb, Vb, Ab);
  gemm_out_kernel<<<dim3(64, 16), dim3(256), 0, stream>>>(Ab, Wo, Out);
}

// Round 4
// 294.638 us; speedup vs baseline: 1.2359x; 1.2359x over previous
//
#include <hip/hip_runtime.h>
#include <hip/hip_bf16.h>
#include <math.h>

#define NHEADS 16
#define DKH 64
#define SEQ 2048
#define DMODEL 1024

typedef __attribute__((ext_vector_type(8))) short short8;
typedef __attribute__((ext_vector_type(4))) float f32x4;

__device__ __forceinline__ short f2bf(float f) {
  unsigned u = __float_as_uint(f);
  unsigned r = (u + 0x7fffu + ((u >> 16) & 1u)) >> 16;
  return (short)r;
}

__device__ __forceinline__ short8 pack8(float4 a, float4 b) {
  short8 v;
  v[0] = f2bf(a.x); v[1] = f2bf(a.y); v[2] = f2bf(a.z); v[3] = f2bf(a.w);
  v[4] = f2bf(b.x); v[5] = f2bf(b.y); v[6] = f2bf(b.z); v[7] = f2bf(b.w);
  return v;
}

// Swizzled LDS tile [rows][64] bf16. Granule = 8 elems (16B).
// Element (r,c) lives at short index r*64 + (((c>>3) ^ (r&7))<<3) + (c&7).
__device__ __forceinline__ int swz(int r, int gran) {
  return r * 64 + ((gran ^ (r & 7)) << 3);
}

// ---------------- RoPE cos/sin table ----------------
__global__ void rope_table_kernel(const int* __restrict__ tp,
                                  float* __restrict__ ct, float* __restrict__ st) {
  int idx = blockIdx.x * 256 + threadIdx.x;
  if (idx >= SEQ * 32) return;
  int s = idx >> 5, i = idx & 31;
  int is64 = (tp[1] == 0);
  int p = is64 ? tp[2 * s] : tp[s];
  float invf = powf(10000.0f, -(2.0f * (float)i) / 64.0f);
  float a = (float)p * invf;
  ct[idx] = cosf(a);
  st[idx] = sinf(a);
}

// ---------------- fused QKV projection + RoPE ----------------
__global__ __launch_bounds__(256) void gemm_qkv_kernel(
    const float* __restrict__ X, const float* __restrict__ Wq,
    const float* __restrict__ Wk, const float* __restrict__ Wv,
    short* __restrict__ Qb, short* __restrict__ Kb, short* __restrict__ Vb,
    const float* __restrict__ ct, const float* __restrict__ st) {
  __shared__ __align__(16) short As[64 * 64];
  __shared__ __align__(16) short Bs[64 * 64];
  const int tm = blockIdx.x;          // 64 row tiles
  const int tn = blockIdx.y;          // 48 col tiles (3*1024/64)
  const int tid = threadIdx.x;
  const int wave = tid >> 6, lane = tid & 63;
  const int l15 = lane & 15, quad = lane >> 4;

  const int mid = (tn * 64) >> 10;     // 0=Q 1=K 2=V
  const int n0 = (tn * 64) & 1023;
  const float* W = (mid == 0) ? Wq : (mid == 1 ? Wk : Wv);
  const float* Arow = X + (size_t)(tm * 64) * DMODEL;
  const float* Wrow = W + (size_t)n0 * DMODEL;

  f32x4 acc[4];
#pragma unroll
  for (int i = 0; i < 4; i++) acc[i] = (f32x4){0.f, 0.f, 0.f, 0.f};

  for (int kk = 0; kk < DMODEL; kk += 64) {
#pragma unroll
    for (int i = 0; i < 2; i++) {
      int g = tid + i * 256;
      int r = g >> 3, c = g & 7;
      const float* ap = Arow + (size_t)r * DMODEL + kk + c * 8;
      float4 a0 = *reinterpret_cast<const float4*>(ap);
      float4 a1 = *reinterpret_cast<const float4*>(ap + 4);
      *reinterpret_cast<short8*>(&As[swz(r, c)]) = pack8(a0, a1);
      const float* bp = Wrow + (size_t)r * DMODEL + kk + c * 8;
      float4 b0 = *reinterpret_cast<const float4*>(bp);
      float4 b1 = *reinterpret_cast<const float4*>(bp + 4);
      *reinterpret_cast<short8*>(&Bs[swz(r, c)]) = pack8(b0, b1);
    }
    __syncthreads();
    short8 af0, af1;
    {
      int r = wave * 16 + l15;
      af0 = *reinterpret_cast<const short8*>(&As[swz(r, quad)]);
      af1 = *reinterpret_cast<const short8*>(&As[swz(r, 4 + quad)]);
    }
#pragma unroll
    for (int nb = 0; nb < 4; nb++) {
      int r = nb * 16 + l15;
      short8 bf0 = *reinterpret_cast<const short8*>(&Bs[swz(r, quad)]);
      acc[nb] = __builtin_amdgcn_mfma_f32_16x16x32_bf16(af0, bf0, acc[nb], 0, 0, 0);
      short8 bf1 = *reinterpret_cast<const short8*>(&Bs[swz(r, 4 + quad)]);
      acc[nb] = __builtin_amdgcn_mfma_f32_16x16x32_bf16(af1, bf1, acc[nb], 0, 0, 0);
    }
    __syncthreads();
  }
#pragma unroll
  for (int nb = 0; nb < 4; nb++) {
    int nl = n0 + nb * 16 + l15;
    int h = nl >> 6, dd = nl & 63;
#pragma unroll
    for (int reg = 0; reg < 4; reg++) {
      int rg = tm * 64 + wave * 16 + quad * 4 + reg;
      int b = rg >> 11, s = rg & 2047;
      float v = acc[nb][reg];
      size_t oi = (((size_t)(b * NHEADS + h)) * SEQ + s) * DKH + dd;
      if (mid == 2) {
        Vb[oi] = f2bf(v);
      } else {
        float pv = __shfl_xor(v, 1);
        int fi = dd >> 1;
        float c = ct[s * 32 + fi], sn = st[s * 32 + fi];
        float o = (dd & 1) ? (pv * sn + v * c) : (v * c - pv * sn);
        ((mid == 0) ? Qb : Kb)[oi] = f2bf(o);
      }
    }
  }
}

// ---------------- flash attention (causal), round 4 ----------------
// - 1D grid, XCD/CU-balanced qt remap: each CU gets qt set {31-x,16+x,15-x,x}
// - double-buffered Ks/Vs, prefetch kt+1 during compute, ONE barrier/iter
// - V-transpose scatter swizzle (key>>3)^(dv&7)^(dv>>3): conflict-free writes
// - base-2 softmax (log2e folded into 1/sqrt(d) scale)
__global__ __launch_bounds__(256) void attn_kernel(
    const short* __restrict__ Qb, const short* __restrict__ Kb,
    const short* __restrict__ Vb, short* __restrict__ Ob) {
  __shared__ __align__(16) short Qs[64 * 64];
  __shared__ __align__(16) short Ks[2][64 * 64];
  __shared__ __align__(16) short Vs[2][64 * 64];   // transposed: [dv][key]
  __shared__ __align__(16) short Ps[4][16 * 64];   // per-wave P tile

  const int id = blockIdx.x;
  const int xx = id & 7;
  const int mm = (((id >> 3) & 3) + (id >> 8)) & 3;
  const int bh = id >> 5;
  const int qt = (mm == 0) ? (31 - xx) : (mm == 1) ? (16 + xx)
               : (mm == 2) ? (15 - xx) : xx;

  const int tid = threadIdx.x;
  const int wave = tid >> 6, lane = tid & 63;
  const int l15 = lane & 15, quad = lane >> 4;
  const int sr0 = tid >> 3;     // staging row for i=0 (i=1: +32)
  const int sc = tid & 7;       // staging granule col

  const short* Qp = Qb + (size_t)bh * SEQ * DKH;
  const short* Kp = Kb + (size_t)bh * SEQ * DKH;
  const short* Vp = Vb + (size_t)bh * SEQ * DKH;

  uint4 kreg[2], vreg[2];
  // preload K/V tile 0
#pragma unroll
  for (int i = 0; i < 2; i++) {
    int r = sr0 + i * 32;
    kreg[i] = *reinterpret_cast<const uint4*>(Kp + (size_t)r * DKH + sc * 8);
    vreg[i] = *reinterpret_cast<const uint4*>(Vp + (size_t)r * DKH + sc * 8);
  }
  // stage Q
#pragma unroll
  for (int i = 0; i < 2; i++) {
    int r = sr0 + i * 32;
    uint4 v = *reinterpret_cast<const uint4*>(Qp + (size_t)(qt * 64 + r) * DKH + sc * 8);
    *reinterpret_cast<uint4*>(&Qs[swz(r, sc)]) = v;
  }
  // write tile 0 into buffer 0
#pragma unroll
  for (int i = 0; i < 2; i++) {
    int r = sr0 + i * 32;
    *reinterpret_cast<uint4*>(&Ks[0][swz(r, sc)]) = kreg[i];
    const short* vsp = reinterpret_cast<const short*>(&vreg[i]);
#pragma unroll
    for (int j = 0; j < 8; j++) {
      int dv = sc * 8 + j;
      Vs[0][dv * 64 + ((((r >> 3) ^ (dv & 7) ^ (dv >> 3)) & 7) << 3) + (r & 7)] = vsp[j];
    }
  }
  __syncthreads();
  short8 qf0, qf1;
  {
    int r = wave * 16 + l15;
    qf0 = *reinterpret_cast<const short8*>(&Qs[swz(r, quad)]);
    qf1 = *reinterpret_cast<const short8*>(&Qs[swz(r, 4 + quad)]);
  }

  f32x4 accO[4];
#pragma unroll
  for (int i = 0; i < 4; i++) accO[i] = (f32x4){0.f, 0.f, 0.f, 0.f};
  float mrow[4] = {-1e30f, -1e30f, -1e30f, -1e30f};
  float lrow[4] = {0.f, 0.f, 0.f, 0.f};

  const float SCL = 0.125f * 1.44269504089f;   // 1/sqrt(64) * log2(e)

  int buf = 0;
  for (int kt = 0; kt <= qt; kt++) {
    // prefetch next K/V tile (in flight during compute)
    if (kt < qt) {
#pragma unroll
      for (int i = 0; i < 2; i++) {
        int r = (kt + 1) * 64 + sr0 + i * 32;
        kreg[i] = *reinterpret_cast<const uint4*>(Kp + (size_t)r * DKH + sc * 8);
        vreg[i] = *reinterpret_cast<const uint4*>(Vp + (size_t)r * DKH + sc * 8);
      }
    }

    // S = Q K^T (base-2 scaled), causal mask on diagonal tile
    f32x4 sa[4];
#pragma unroll
    for (int nb = 0; nb < 4; nb++) {
      sa[nb] = (f32x4){0.f, 0.f, 0.f, 0.f};
      int r = nb * 16 + l15;
      short8 kf0 = *reinterpret_cast<const short8*>(&Ks[buf][swz(r, quad)]);
      sa[nb] = __builtin_amdgcn_mfma_f32_16x16x32_bf16(qf0, kf0, sa[nb], 0, 0, 0);
      short8 kf1 = *reinterpret_cast<const short8*>(&Ks[buf][swz(r, 4 + quad)]);
      sa[nb] = __builtin_amdgcn_mfma_f32_16x16x32_bf16(qf1, kf1, sa[nb], 0, 0, 0);
    }
    float sv[4][4];
#pragma unroll
    for (int nb = 0; nb < 4; nb++)
#pragma unroll
      for (int reg = 0; reg < 4; reg++) {
        float x = sa[nb][reg] * SCL;
        if (kt == qt && (nb * 16 + l15) > (wave * 16 + quad * 4 + reg)) x = -1e30f;
        sv[nb][reg] = x;
      }
    float mnew[4], alpha[4];
#pragma unroll
    for (int reg = 0; reg < 4; reg++) {
      float rm = fmaxf(fmaxf(sv[0][reg], sv[1][reg]), fmaxf(sv[2][reg], sv[3][reg]));
#pragma unroll
      for (int off = 1; off < 16; off <<= 1) rm = fmaxf(rm, __shfl_xor(rm, off));
      mnew[reg] = fmaxf(mrow[reg], rm);
      alpha[reg] = exp2f(mrow[reg] - mnew[reg]);
      mrow[reg] = mnew[reg];
    }
    float rs[4] = {0.f, 0.f, 0.f, 0.f};
#pragma unroll
    for (int nb = 0; nb < 4; nb++)
#pragma unroll
      for (int reg = 0; reg < 4; reg++) {
        float p = exp2f(sv[nb][reg] - mnew[reg]);
        rs[reg] += p;
        int r = quad * 4 + reg, col = nb * 16 + l15;
        Ps[wave][r * 64 + (((col >> 3) ^ (r & 7)) << 3) + (col & 7)] = f2bf(p);
      }
#pragma unroll
    for (int reg = 0; reg < 4; reg++) {
      float t = rs[reg];
#pragma unroll
      for (int off = 1; off < 16; off <<= 1) t += __shfl_xor(t, off);
      lrow[reg] = lrow[reg] * alpha[reg] + t;
    }
#pragma unroll
    for (int db = 0; db < 4; db++)
#pragma unroll
      for (int reg = 0; reg < 4; reg++) accO[db][reg] *= alpha[reg];

    // O += P V  (Ps is per-wave: same-wave LDS write->read, no barrier)
    short8 pf0, pf1;
    {
      pf0 = *reinterpret_cast<const short8*>(&Ps[wave][swz(l15, quad)]);
      pf1 = *reinterpret_cast<const short8*>(&Ps[wave][swz(l15, 4 + quad)]);
    }
#pragma unroll
    for (int db = 0; db < 4; db++) {
      int dv = db * 16 + l15;
      int fsw = (dv & 7) ^ (dv >> 3);
      short8 vf0 = *reinterpret_cast<const short8*>(
          &Vs[buf][dv * 64 + (((quad ^ fsw) & 7) << 3)]);
      accO[db] = __builtin_amdgcn_mfma_f32_16x16x32_bf16(pf0, vf0, accO[db], 0, 0, 0);
      short8 vf1 = *reinterpret_cast<const short8*>(
          &Vs[buf][dv * 64 + ((((quad + 4) ^ fsw) & 7) << 3)]);
      accO[db] = __builtin_amdgcn_mfma_f32_16x16x32_bf16(pf1, vf1, accO[db], 0, 0, 0);
    }

    // write prefetched tile into spare buffer; one barrier per iteration
    if (kt < qt) {
      int nbuf = buf ^ 1;
#pragma unroll
      for (int i = 0; i < 2; i++) {
        int r = sr0 + i * 32;
        *reinterpret_cast<uint4*>(&Ks[nbuf][swz(r, sc)]) = kreg[i];
        const short* vsp = reinterpret_cast<const short*>(&vreg[i]);
#pragma unroll
        for (int j = 0; j < 8; j++) {
          int dv = sc * 8 + j;
          Vs[nbuf][dv * 64 + ((((r >> 3) ^ (dv & 7) ^ (dv >> 3)) & 7) << 3) + (r & 7)] = vsp[j];
        }
      }
      __syncthreads();
      buf = nbuf;
    }
  }

  // write (B,S,1024) bf16
  int b = bh >> 4, h = bh & 15;
#pragma unroll
  for (int db = 0; db < 4; db++)
#pragma unroll
    for (int reg = 0; reg < 4; reg++) {
      int s = qt * 64 + wave * 16 + quad * 4 + reg;
      int dv = db * 16 + l15;
      float o = accO[db][reg] / lrow[reg];
      Ob[((size_t)(b * SEQ + s)) * DMODEL + h * DKH + dv] = f2bf(o);
    }
}

// ---------------- output projection (fp32 output) ----------------
__global__ __launch_bounds__(256) void gemm_out_kernel(
    const short* __restrict__ X, const float* __restrict__ Wo, float* __restrict__ Out) {
  __shared__ __align__(16) short As[64 * 64];
  __shared__ __align__(16) short Bs[64 * 64];
  const int tm = blockIdx.x;   // 64
  const int tn = blockIdx.y;   // 16
  const int tid = threadIdx.x;
  const int wave = tid >> 6, lane = tid & 63;
  const int l15 = lane & 15, quad = lane >> 4;

  const short* Arow = X + (size_t)(tm * 64) * DMODEL;
  const float* Wrow = Wo + (size_t)(tn * 64) * DMODEL;

  f32x4 acc[4];
#pragma unroll
  for (int i = 0; i < 4; i++) acc[i] = (f32x4){0.f, 0.f, 0.f, 0.f};

  for (int kk = 0; kk < DMODEL; kk += 64) {
#pragma unroll
    for (int i = 0; i < 2; i++) {
      int g = tid + i * 256;
      int r = g >> 3, c = g & 7;
      uint4 va = *reinterpret_cast<const uint4*>(Arow + (size_t)r * DMODEL + kk + c * 8);
      *reinterpret_cast<uint4*>(&As[swz(r, c)]) = va;
      const float* bp = Wrow + (size_t)r * DMODEL + kk + c * 8;
      float4 b0 = *reinterpret_cast<const float4*>(bp);
      float4 b1 = *reinterpret_cast<const float4*>(bp + 4);
      *reinterpret_cast<short8*>(&Bs[swz(r, c)]) = pack8(b0, b1);
    }
    __syncthreads();
    short8 af0, af1;
    {
      int r = wave * 16 + l15;
      af0 = *reinterpret_cast<const short8*>(&As[swz(r, quad)]);
      af1 = *reinterpret_cast<const short8*>(&As[swz(r, 4 + quad)]);
    }
#pragma unroll
    for (int nb = 0; nb < 4; nb++) {
      int r = nb * 16 + l15;
      short8 bf0 = *reinterpret_cast<const short8*>(&Bs[swz(r, quad)]);
      acc[nb] = __builtin_amdgcn_mfma_f32_16x16x32_bf16(af0, bf0, acc[nb], 0, 0, 0);
      short8 bf1 = *reinterpret_cast<const short8*>(&Bs[swz(r, 4 + quad)]);
      acc[nb] = __builtin_amdgcn_mfma_f32_16x16x32_bf16(af1, bf1, acc[nb], 0, 0, 0);
    }
    __syncthreads();
  }
#pragma unroll
  for (int nb = 0; nb < 4; nb++)
#pragma unroll
    for (int reg = 0; reg < 4; reg++) {
      int rg = tm * 64 + wave * 16 + quad * 4 + reg;
      int col = tn * 64 + nb * 16 + l15;
      Out[(size_t)rg * DMODEL + col] = acc[nb][reg];
    }
}

extern "C" void kernel_launch(void* const* d_in, const int* in_sizes, int n_in,
                              void* d_out, int out_size, void* d_ws, size_t ws_size,
                              hipStream_t stream) {
  (void)in_sizes; (void)n_in; (void)out_size; (void)ws_size;
  const float* X  = (const float*)d_in[0];
  const int*   tp = (const int*)d_in[1];
  const float* Wq = (const float*)d_in[2];
  const float* Wk = (const float*)d_in[3];
  const float* Wv = (const float*)d_in[4];
  const float* Wo = (const float*)d_in[5];
  float* Out = (float*)d_out;

  short* Qb = (short*)d_ws;            // 4194304 bf16 each
  short* Kb = Qb + 4194304;
  short* Vb = Kb + 4194304;
  short* Ab = Vb + 4194304;
  float* ct = (float*)(Ab + 4194304);  // 65536 floats
  float* st = ct + SEQ * 32;

  rope_table_kernel<<<dim3(256), dim3(256), 0, stream>>>(tp, ct, st);
  gemm_qkv_kernel<<<dim3(64, 48), dim3(256), 0, stream>>>(X, Wq, Wk, Wv, Qb, Kb, Vb, ct, st);
  attn_kernel<<<dim3(1024), dim3(256), 0, stream>>>(Qb, Kb, Vb, Ab);
  gemm_out_kernel<<<dim3(64, 16), dim3(256), 0, stream>>>(Ab, Wo, Out);
}

// Round 5
// 288.025 us; speedup vs baseline: 1.2643x; 1.0230x over previous
//
#include <hip/hip_runtime.h>
#include <hip/hip_bf16.h>
#include <math.h>

#define NHEADS 16
#define DKH 64
#define SEQ 2048
#define DMODEL 1024

typedef __attribute__((ext_vector_type(8))) short short8;
typedef __attribute__((ext_vector_type(4))) float f32x4;

__device__ __forceinline__ short f2bf(float f) {
  unsigned u = __float_as_uint(f);
  unsigned r = (u + 0x7fffu + ((u >> 16) & 1u)) >> 16;
  return (short)r;
}

__device__ __forceinline__ short8 pack8(float4 a, float4 b) {
  short8 v;
  v[0] = f2bf(a.x); v[1] = f2bf(a.y); v[2] = f2bf(a.z); v[3] = f2bf(a.w);
  v[4] = f2bf(b.x); v[5] = f2bf(b.y); v[6] = f2bf(b.z); v[7] = f2bf(b.w);
  return v;
}

// Swizzled LDS tile [rows][64] bf16. Granule = 8 elems (16B).
// Element (r,c) at short index r*64 + (((c>>3) ^ (r&7))<<3) + (c&7).
__device__ __forceinline__ int swz(int r, int gran) {
  return r * 64 + ((gran ^ (r & 7)) << 3);
}

// ---------------- RoPE cos/sin table ----------------
__global__ void rope_table_kernel(const int* __restrict__ tp,
                                  float* __restrict__ ct, float* __restrict__ st) {
  int idx = blockIdx.x * 256 + threadIdx.x;
  if (idx >= SEQ * 32) return;
  int s = idx >> 5, i = idx & 31;
  int is64 = (tp[1] == 0);
  int p = is64 ? tp[2 * s] : tp[s];
  float invf = powf(10000.0f, -(2.0f * (float)i) / 64.0f);
  float a = (float)p * invf;
  ct[idx] = cosf(a);
  st[idx] = sinf(a);
}

// ---------------- precast fp32 -> bf16 (X, Wq, Wk, Wv, Wo) ----------------
// group = 8 elements. X: 512K groups; each W: 128K groups. total 1M groups.
__global__ __launch_bounds__(256) void precast_kernel(
    const float* __restrict__ X, const float* __restrict__ Wq,
    const float* __restrict__ Wk, const float* __restrict__ Wv,
    const float* __restrict__ Wo,
    short* __restrict__ Xb, short* __restrict__ Wqb, short* __restrict__ Wkb,
    short* __restrict__ Wvb, short* __restrict__ Wob) {
  int i = blockIdx.x * 256 + threadIdx.x;
  const float* src; short* dst; int off;
  if (i < 524288) { src = X; dst = Xb; off = i; }
  else {
    int k = i - 524288; int w = k >> 17; off = k & 131071;
    src = (w == 0) ? Wq : (w == 1) ? Wk : (w == 2) ? Wv : Wo;
    dst = (w == 0) ? Wqb : (w == 1) ? Wkb : (w == 2) ? Wvb : Wob;
  }
  const float4* p = reinterpret_cast<const float4*>(src) + 2 * (size_t)off;
  float4 a = p[0], b = p[1];
  reinterpret_cast<short8*>(dst)[off] = pack8(a, b);
}

// ---------------- fused QKV projection + RoPE (bf16 inputs) ----------------
__global__ __launch_bounds__(256) void gemm_qkv_kernel(
    const short* __restrict__ X, const short* __restrict__ Wq,
    const short* __restrict__ Wk, const short* __restrict__ Wv,
    short* __restrict__ Qb, short* __restrict__ Kb, short* __restrict__ Vb,
    const float* __restrict__ ct, const float* __restrict__ st) {
  __shared__ __align__(16) short As[64 * 64];
  __shared__ __align__(16) short Bs[64 * 64];
  const int tm = blockIdx.x;          // 64 row tiles
  const int tn = blockIdx.y;          // 48 col tiles
  const int tid = threadIdx.x;
  const int wave = tid >> 6, lane = tid & 63;
  const int l15 = lane & 15, quad = lane >> 4;

  const int mid = (tn * 64) >> 10;     // 0=Q 1=K 2=V
  const int n0 = (tn * 64) & 1023;
  const short* W = (mid == 0) ? Wq : (mid == 1 ? Wk : Wv);
  const short* Arow = X + (size_t)(tm * 64) * DMODEL;
  const short* Wrow = W + (size_t)n0 * DMODEL;

  f32x4 acc[4];
#pragma unroll
  for (int i = 0; i < 4; i++) acc[i] = (f32x4){0.f, 0.f, 0.f, 0.f};

  for (int kk = 0; kk < DMODEL; kk += 64) {
#pragma unroll
    for (int i = 0; i < 2; i++) {
      int g = tid + i * 256;
      int r = g >> 3, c = g & 7;
      uint4 va = *reinterpret_cast<const uint4*>(Arow + (size_t)r * DMODEL + kk + c * 8);
      *reinterpret_cast<uint4*>(&As[swz(r, c)]) = va;
      uint4 vb = *reinterpret_cast<const uint4*>(Wrow + (size_t)r * DMODEL + kk + c * 8);
      *reinterpret_cast<uint4*>(&Bs[swz(r, c)]) = vb;
    }
    __syncthreads();
    short8 af0, af1;
    {
      int r = wave * 16 + l15;
      af0 = *reinterpret_cast<const short8*>(&As[swz(r, quad)]);
      af1 = *reinterpret_cast<const short8*>(&As[swz(r, 4 + quad)]);
    }
#pragma unroll
    for (int nb = 0; nb < 4; nb++) {
      int r = nb * 16 + l15;
      short8 bf0 = *reinterpret_cast<const short8*>(&Bs[swz(r, quad)]);
      acc[nb] = __builtin_amdgcn_mfma_f32_16x16x32_bf16(af0, bf0, acc[nb], 0, 0, 0);
      short8 bf1 = *reinterpret_cast<const short8*>(&Bs[swz(r, 4 + quad)]);
      acc[nb] = __builtin_amdgcn_mfma_f32_16x16x32_bf16(af1, bf1, acc[nb], 0, 0, 0);
    }
    __syncthreads();
  }
#pragma unroll
  for (int nb = 0; nb < 4; nb++) {
    int nl = n0 + nb * 16 + l15;
    int h = nl >> 6, dd = nl & 63;
#pragma unroll
    for (int reg = 0; reg < 4; reg++) {
      int rg = tm * 64 + wave * 16 + quad * 4 + reg;
      int b = rg >> 11, s = rg & 2047;
      float v = acc[nb][reg];
      size_t oi = (((size_t)(b * NHEADS + h)) * SEQ + s) * DKH + dd;
      if (mid == 2) {
        Vb[oi] = f2bf(v);
      } else {
        float pv = __shfl_xor(v, 1);
        int fi = dd >> 1;
        float c = ct[s * 32 + fi], sn = st[s * 32 + fi];
        float o = (dd & 1) ? (pv * sn + v * c) : (v * c - pv * sn);
        ((mid == 0) ? Qb : Kb)[oi] = f2bf(o);
      }
    }
  }
}

// ---------------- flash attention (causal), round 5: BM=128 ----------------
// Each wave owns two 16-row M-frags (halves h=0,1) -> 2x ILP on softmax chain.
// 512 blocks x 64KB LDS = 2 blocks/CU co-resident. Cost-paired qt remap:
// CU slot j gets qt=15-(j&15) (first 256 ids) and qt=(j&15) (second 256).
__global__ __launch_bounds__(256, 2) void attn_kernel(
    const short* __restrict__ Qb, const short* __restrict__ Kb,
    const short* __restrict__ Vb, short* __restrict__ Ob) {
  __shared__ __align__(16) short Qs[128 * 64];
  __shared__ __align__(16) short Ks[2][64 * 64];
  __shared__ __align__(16) short Vs[2][64 * 64];   // transposed: [dv][key]
  __shared__ __align__(16) short Ps[4][32 * 64];   // per-wave, rows h*16+m

  const int id = blockIdx.x;
  const int j = id & 255, hi = id >> 8;
  const int qt = hi ? (j & 15) : (15 - (j & 15));   // 0..15 (128-row tiles)
  const int bh = (j >> 4) + (hi << 4);              // 0..31

  const int tid = threadIdx.x;
  const int wave = tid >> 6, lane = tid & 63;
  const int l15 = lane & 15, quad = lane >> 4;
  const int sr0 = tid >> 3, sc = tid & 7;

  const short* Qp = Qb + (size_t)bh * SEQ * DKH;
  const short* Kp = Kb + (size_t)bh * SEQ * DKH;
  const short* Vp = Vb + (size_t)bh * SEQ * DKH;

  uint4 kreg[2], vreg[2];
#pragma unroll
  for (int i = 0; i < 2; i++) {
    int r = sr0 + i * 32;
    kreg[i] = *reinterpret_cast<const uint4*>(Kp + (size_t)r * DKH + sc * 8);
    vreg[i] = *reinterpret_cast<const uint4*>(Vp + (size_t)r * DKH + sc * 8);
  }
  // stage Q (128 rows)
#pragma unroll
  for (int i = 0; i < 4; i++) {
    int r = sr0 + i * 32;
    uint4 v = *reinterpret_cast<const uint4*>(Qp + (size_t)(qt * 128 + r) * DKH + sc * 8);
    *reinterpret_cast<uint4*>(&Qs[swz(r, sc)]) = v;
  }
  // K/V tile 0 into buffer 0
#pragma unroll
  for (int i = 0; i < 2; i++) {
    int r = sr0 + i * 32;
    *reinterpret_cast<uint4*>(&Ks[0][swz(r, sc)]) = kreg[i];
    const short* vsp = reinterpret_cast<const short*>(&vreg[i]);
#pragma unroll
    for (int jj = 0; jj < 8; jj++) {
      int dv = sc * 8 + jj;
      Vs[0][dv * 64 + ((((r >> 3) ^ (dv & 7) ^ (dv >> 3)) & 7) << 3) + (r & 7)] = vsp[jj];
    }
  }
  __syncthreads();
  short8 qf[2][2];
#pragma unroll
  for (int h = 0; h < 2; h++) {
    int r = h * 64 + wave * 16 + l15;
    qf[h][0] = *reinterpret_cast<const short8*>(&Qs[swz(r, quad)]);
    qf[h][1] = *reinterpret_cast<const short8*>(&Qs[swz(r, 4 + quad)]);
  }

  f32x4 accO[2][4];
  float mrow[2][4], lrow[2][4];
#pragma unroll
  for (int h = 0; h < 2; h++)
#pragma unroll
    for (int i = 0; i < 4; i++) {
      accO[h][i] = (f32x4){0.f, 0.f, 0.f, 0.f};
      mrow[h][i] = -1e30f; lrow[h][i] = 0.f;
    }

  const float SCL = 0.125f * 1.44269504089f;   // 1/sqrt(64) * log2(e)
  const int KT = 2 * qt + 2;
  int buf = 0;

  for (int kt = 0; kt < KT; kt++) {
    if (kt < KT - 1) {
#pragma unroll
      for (int i = 0; i < 2; i++) {
        int r = (kt + 1) * 64 + sr0 + i * 32;
        kreg[i] = *reinterpret_cast<const uint4*>(Kp + (size_t)r * DKH + sc * 8);
        vreg[i] = *reinterpret_cast<const uint4*>(Vp + (size_t)r * DKH + sc * 8);
      }
    }
    const int hstart = (kt > 2 * qt) ? 1 : 0;   // last tile: upper half fully masked

    // S = Q K^T (both halves share kf reads)
    f32x4 sa[2][4];
#pragma unroll
    for (int nb = 0; nb < 4; nb++) {
      int r = nb * 16 + l15;
      short8 kf0 = *reinterpret_cast<const short8*>(&Ks[buf][swz(r, quad)]);
      short8 kf1 = *reinterpret_cast<const short8*>(&Ks[buf][swz(r, 4 + quad)]);
#pragma unroll
      for (int h = 0; h < 2; h++) {
        if (h < hstart) continue;
        sa[h][nb] = (f32x4){0.f, 0.f, 0.f, 0.f};
        sa[h][nb] = __builtin_amdgcn_mfma_f32_16x16x32_bf16(qf[h][0], kf0, sa[h][nb], 0, 0, 0);
        sa[h][nb] = __builtin_amdgcn_mfma_f32_16x16x32_bf16(qf[h][1], kf1, sa[h][nb], 0, 0, 0);
      }
    }

    float alpha[2][4];
#pragma unroll
    for (int h = 0; h < 2; h++) {
      if (h < hstart) continue;
      const int diag = (kt == 2 * qt + h);
      float sv[4][4];
#pragma unroll
      for (int nb = 0; nb < 4; nb++)
#pragma unroll
        for (int reg = 0; reg < 4; reg++) {
          float x = sa[h][nb][reg] * SCL;
          if (diag && (nb * 16 + l15) > (wave * 16 + quad * 4 + reg)) x = -1e30f;
          sv[nb][reg] = x;
        }
      float mnew[4];
#pragma unroll
      for (int reg = 0; reg < 4; reg++) {
        float rm = fmaxf(fmaxf(sv[0][reg], sv[1][reg]), fmaxf(sv[2][reg], sv[3][reg]));
#pragma unroll
        for (int off = 1; off < 16; off <<= 1) rm = fmaxf(rm, __shfl_xor(rm, off));
        mnew[reg] = fmaxf(mrow[h][reg], rm);
        alpha[h][reg] = exp2f(mrow[h][reg] - mnew[reg]);
        mrow[h][reg] = mnew[reg];
      }
      float rs[4] = {0.f, 0.f, 0.f, 0.f};
#pragma unroll
      for (int nb = 0; nb < 4; nb++)
#pragma unroll
        for (int reg = 0; reg < 4; reg++) {
          float p = exp2f(sv[nb][reg] - mnew[reg]);
          rs[reg] += p;
          int r = h * 16 + quad * 4 + reg, col = nb * 16 + l15;
          Ps[wave][r * 64 + (((col >> 3) ^ (r & 7)) << 3) + (col & 7)] = f2bf(p);
        }
#pragma unroll
      for (int reg = 0; reg < 4; reg++) {
        float t = rs[reg];
#pragma unroll
        for (int off = 1; off < 16; off <<= 1) t += __shfl_xor(t, off);
        lrow[h][reg] = lrow[h][reg] * alpha[h][reg] + t;
      }
#pragma unroll
      for (int db = 0; db < 4; db++)
#pragma unroll
        for (int reg = 0; reg < 4; reg++) accO[h][db][reg] *= alpha[h][reg];
    }

    // O += P V  (per-wave Ps: same-wave write->read, no barrier)
    short8 pf[2][2];
#pragma unroll
    for (int h = 0; h < 2; h++) {
      if (h < hstart) continue;
      int r = h * 16 + l15;
      pf[h][0] = *reinterpret_cast<const short8*>(&Ps[wave][swz(r, quad)]);
      pf[h][1] = *reinterpret_cast<const short8*>(&Ps[wave][swz(r, 4 + quad)]);
    }
#pragma unroll
    for (int db = 0; db < 4; db++) {
      int dv = db * 16 + l15;
      int fsw = (dv & 7) ^ (dv >> 3);
      short8 vf0 = *reinterpret_cast<const short8*>(
          &Vs[buf][dv * 64 + (((quad ^ fsw) & 7) << 3)]);
      short8 vf1 = *reinterpret_cast<const short8*>(
          &Vs[buf][dv * 64 + ((((quad + 4) ^ fsw) & 7) << 3)]);
#pragma unroll
      for (int h = 0; h < 2; h++) {
        if (h < hstart) continue;
        accO[h][db] = __builtin_amdgcn_mfma_f32_16x16x32_bf16(pf[h][0], vf0, accO[h][db], 0, 0, 0);
        accO[h][db] = __builtin_amdgcn_mfma_f32_16x16x32_bf16(pf[h][1], vf1, accO[h][db], 0, 0, 0);
      }
    }

    if (kt < KT - 1) {
      int nbuf = buf ^ 1;
#pragma unroll
      for (int i = 0; i < 2; i++) {
        int r = sr0 + i * 32;
        *reinterpret_cast<uint4*>(&Ks[nbuf][swz(r, sc)]) = kreg[i];
        const short* vsp = reinterpret_cast<const short*>(&vreg[i]);
#pragma unroll
        for (int jj = 0; jj < 8; jj++) {
          int dv = sc * 8 + jj;
          Vs[nbuf][dv * 64 + ((((r >> 3) ^ (dv & 7) ^ (dv >> 3)) & 7) << 3) + (r & 7)] = vsp[jj];
        }
      }
      __syncthreads();
      buf = nbuf;
    }
  }

  // write (B,S,1024) bf16
  int b = bh >> 4, hd = bh & 15;
#pragma unroll
  for (int h = 0; h < 2; h++)
#pragma unroll
    for (int db = 0; db < 4; db++)
#pragma unroll
      for (int reg = 0; reg < 4; reg++) {
        int s = qt * 128 + h * 64 + wave * 16 + quad * 4 + reg;
        int dv = db * 16 + l15;
        float o = accO[h][db][reg] / lrow[h][reg];
        Ob[((size_t)(b * SEQ + s)) * DMODEL + hd * DKH + dv] = f2bf(o);
      }
}

// ---------------- output projection (bf16 inputs, fp32 output) ----------------
__global__ __launch_bounds__(256) void gemm_out_kernel(
    const short* __restrict__ X, const short* __restrict__ Wo, float* __restrict__ Out) {
  __shared__ __align__(16) short As[64 * 64];
  __shared__ __align__(16) short Bs[64 * 64];
  const int tm = blockIdx.x;   // 64
  const int tn = blockIdx.y;   // 16
  const int tid = threadIdx.x;
  const int wave = tid >> 6, lane = tid & 63;
  const int l15 = lane & 15, quad = lane >> 4;

  const short* Arow = X + (size_t)(tm * 64) * DMODEL;
  const short* Wrow = Wo + (size_t)(tn * 64) * DMODEL;

  f32x4 acc[4];
#pragma unroll
  for (int i = 0; i < 4; i++) acc[i] = (f32x4){0.f, 0.f, 0.f, 0.f};

  for (int kk = 0; kk < DMODEL; kk += 64) {
#pragma unroll
    for (int i = 0; i < 2; i++) {
      int g = tid + i * 256;
      int r = g >> 3, c = g & 7;
      uint4 va = *reinterpret_cast<const uint4*>(Arow + (size_t)r * DMODEL + kk + c * 8);
      *reinterpret_cast<uint4*>(&As[swz(r, c)]) = va;
      uint4 vb = *reinterpret_cast<const uint4*>(Wrow + (size_t)r * DMODEL + kk + c * 8);
      *reinterpret_cast<uint4*>(&Bs[swz(r, c)]) = vb;
    }
    __syncthreads();
    short8 af0, af1;
    {
      int r = wave * 16 + l15;
      af0 = *reinterpret_cast<const short8*>(&As[swz(r, quad)]);
      af1 = *reinterpret_cast<const short8*>(&As[swz(r, 4 + quad)]);
    }
#pragma unroll
    for (int nb = 0; nb < 4; nb++) {
      int r = nb * 16 + l15;
      short8 bf0 = *reinterpret_cast<const short8*>(&Bs[swz(r, quad)]);
      acc[nb] = __builtin_amdgcn_mfma_f32_16x16x32_bf16(af0, bf0, acc[nb], 0, 0, 0);
      short8 bf1 = *reinterpret_cast<const short8*>(&Bs[swz(r, 4 + quad)]);
      acc[nb] = __builtin_amdgcn_mfma_f32_16x16x32_bf16(af1, bf1, acc[nb], 0, 0, 0);
    }
    __syncthreads();
  }
#pragma unroll
  for (int nb = 0; nb < 4; nb++)
#pragma unroll
    for (int reg = 0; reg < 4; reg++) {
      int rg = tm * 64 + wave * 16 + quad * 4 + reg;
      int col = tn * 64 + nb * 16 + l15;
      Out[(size_t)rg * DMODEL + col] = acc[nb][reg];
    }
}

extern "C" void kernel_launch(void* const* d_in, const int* in_sizes, int n_in,
                              void* d_out, int out_size, void* d_ws, size_t ws_size,
                              hipStream_t stream) {
  (void)in_sizes; (void)n_in; (void)out_size; (void)ws_size;
  const float* X  = (const float*)d_in[0];
  const int*   tp = (const int*)d_in[1];
  const float* Wq = (const float*)d_in[2];
  const float* Wk = (const float*)d_in[3];
  const float* Wv = (const float*)d_in[4];
  const float* Wo = (const float*)d_in[5];
  float* Out = (float*)d_out;

  short* Qb  = (short*)d_ws;           // 4M shorts each
  short* Kb  = Qb + 4194304;
  short* Vb  = Kb + 4194304;
  short* Ab  = Vb + 4194304;
  short* Xb  = Ab + 4194304;           // 4M
  short* Wqb = Xb + 4194304;           // 1M each
  short* Wkb = Wqb + 1048576;
  short* Wvb = Wkb + 1048576;
  short* Wob = Wvb + 1048576;
  float* ct  = (float*)(Wob + 1048576);
  float* st  = ct + SEQ * 32;

  rope_table_kernel<<<dim3(256), dim3(256), 0, stream>>>(tp, ct, st);
  precast_kernel<<<dim3(4096), dim3(256), 0, stream>>>(X, Wq, Wk, Wv, Wo,
                                                       Xb, Wqb, Wkb, Wvb, Wob);
  gemm_qkv_kernel<<<dim3(64, 48), dim3(256), 0, stream>>>(Xb, Wqb, Wkb, Wvb,
                                                          Qb, Kb, Vb, ct, st);
  attn_kernel<<<dim3(512), dim3(256), 0, stream>>>(Qb, Kb, Vb, Ab);
  gemm_out_kernel<<<dim3(64, 16), dim3(256), 0, stream>>>(Ab, Wob, Out);
}

// Round 6
// 213.110 us; speedup vs baseline: 1.7087x; 1.3515x over previous
//
#include <hip/hip_runtime.h>
#include <hip/hip_bf16.h>
#include <math.h>

#define NHEADS 16
#define DKH 64
#define SEQ 2048
#define DMODEL 1024

typedef __attribute__((ext_vector_type(8))) short short8;
typedef __attribute__((ext_vector_type(4))) float f32x4;

__device__ __forceinline__ short f2bf(float f) {
  unsigned u = __float_as_uint(f);
  unsigned r = (u + 0x7fffu + ((u >> 16) & 1u)) >> 16;
  return (short)r;
}

__device__ __forceinline__ short8 pack8(float4 a, float4 b) {
  short8 v;
  v[0] = f2bf(a.x); v[1] = f2bf(a.y); v[2] = f2bf(a.z); v[3] = f2bf(a.w);
  v[4] = f2bf(b.x); v[5] = f2bf(b.y); v[6] = f2bf(b.z); v[7] = f2bf(b.w);
  return v;
}

// Swizzled LDS tile [rows][64] bf16. Granule = 8 elems (16B).
// Element (r,c) at short index r*64 + (((c>>3) ^ (r&7))<<3) + (c&7).
__device__ __forceinline__ int swz(int r, int gran) {
  return r * 64 + ((gran ^ (r & 7)) << 3);
}

// ---------------- RoPE cos/sin table ----------------
__global__ void rope_table_kernel(const int* __restrict__ tp,
                                  float* __restrict__ ct, float* __restrict__ st) {
  int idx = blockIdx.x * 256 + threadIdx.x;
  if (idx >= SEQ * 32) return;
  int s = idx >> 5, i = idx & 31;
  int is64 = (tp[1] == 0);
  int p = is64 ? tp[2 * s] : tp[s];
  float invf = powf(10000.0f, -(2.0f * (float)i) / 64.0f);
  float a = (float)p * invf;
  ct[idx] = cosf(a);
  st[idx] = sinf(a);
}

// ---------------- precast fp32 -> bf16 (X, Wq, Wk, Wv, Wo) ----------------
__global__ __launch_bounds__(256) void precast_kernel(
    const float* __restrict__ X, const float* __restrict__ Wq,
    const float* __restrict__ Wk, const float* __restrict__ Wv,
    const float* __restrict__ Wo,
    short* __restrict__ Xb, short* __restrict__ Wqb, short* __restrict__ Wkb,
    short* __restrict__ Wvb, short* __restrict__ Wob) {
  int i = blockIdx.x * 256 + threadIdx.x;
  const float* src; short* dst; int off;
  if (i < 524288) { src = X; dst = Xb; off = i; }
  else {
    int k = i - 524288; int w = k >> 17; off = k & 131071;
    src = (w == 0) ? Wq : (w == 1) ? Wk : (w == 2) ? Wv : Wo;
    dst = (w == 0) ? Wqb : (w == 1) ? Wkb : (w == 2) ? Wvb : Wob;
  }
  const float4* p = reinterpret_cast<const float4*>(src) + 2 * (size_t)off;
  float4 a = p[0], b = p[1];
  reinterpret_cast<short8*>(dst)[off] = pack8(a, b);
}

// ---------------- fused QKV projection + RoPE (bf16 inputs) ----------------
__global__ __launch_bounds__(256) void gemm_qkv_kernel(
    const short* __restrict__ X, const short* __restrict__ Wq,
    const short* __restrict__ Wk, const short* __restrict__ Wv,
    short* __restrict__ Qb, short* __restrict__ Kb, short* __restrict__ Vb,
    const float* __restrict__ ct, const float* __restrict__ st) {
  __shared__ __align__(16) short As[64 * 64];
  __shared__ __align__(16) short Bs[64 * 64];
  const int tm = blockIdx.x;          // 64 row tiles
  const int tn = blockIdx.y;          // 48 col tiles
  const int tid = threadIdx.x;
  const int wave = tid >> 6, lane = tid & 63;
  const int l15 = lane & 15, quad = lane >> 4;

  const int mid = (tn * 64) >> 10;     // 0=Q 1=K 2=V
  const int n0 = (tn * 64) & 1023;
  const short* W = (mid == 0) ? Wq : (mid == 1 ? Wk : Wv);
  const short* Arow = X + (size_t)(tm * 64) * DMODEL;
  const short* Wrow = W + (size_t)n0 * DMODEL;

  f32x4 acc[4];
#pragma unroll
  for (int i = 0; i < 4; i++) acc[i] = (f32x4){0.f, 0.f, 0.f, 0.f};

  for (int kk = 0; kk < DMODEL; kk += 64) {
#pragma unroll
    for (int i = 0; i < 2; i++) {
      int g = tid + i * 256;
      int r = g >> 3, c = g & 7;
      uint4 va = *reinterpret_cast<const uint4*>(Arow + (size_t)r * DMODEL + kk + c * 8);
      *reinterpret_cast<uint4*>(&As[swz(r, c)]) = va;
      uint4 vb = *reinterpret_cast<const uint4*>(Wrow + (size_t)r * DMODEL + kk + c * 8);
      *reinterpret_cast<uint4*>(&Bs[swz(r, c)]) = vb;
    }
    __syncthreads();
    short8 af0, af1;
    {
      int r = wave * 16 + l15;
      af0 = *reinterpret_cast<const short8*>(&As[swz(r, quad)]);
      af1 = *reinterpret_cast<const short8*>(&As[swz(r, 4 + quad)]);
    }
#pragma unroll
    for (int nb = 0; nb < 4; nb++) {
      int r = nb * 16 + l15;
      short8 bf0 = *reinterpret_cast<const short8*>(&Bs[swz(r, quad)]);
      acc[nb] = __builtin_amdgcn_mfma_f32_16x16x32_bf16(af0, bf0, acc[nb], 0, 0, 0);
      short8 bf1 = *reinterpret_cast<const short8*>(&Bs[swz(r, 4 + quad)]);
      acc[nb] = __builtin_amdgcn_mfma_f32_16x16x32_bf16(af1, bf1, acc[nb], 0, 0, 0);
    }
    __syncthreads();
  }
#pragma unroll
  for (int nb = 0; nb < 4; nb++) {
    int nl = n0 + nb * 16 + l15;
    int h = nl >> 6, dd = nl & 63;
#pragma unroll
    for (int reg = 0; reg < 4; reg++) {
      int rg = tm * 64 + wave * 16 + quad * 4 + reg;
      int b = rg >> 11, s = rg & 2047;
      float v = acc[nb][reg];
      size_t oi = (((size_t)(b * NHEADS + h)) * SEQ + s) * DKH + dd;
      if (mid == 2) {
        Vb[oi] = f2bf(v);
      } else {
        float pv = __shfl_xor(v, 1);
        int fi = dd >> 1;
        float c = ct[s * 32 + fi], sn = st[s * 32 + fi];
        float o = (dd & 1) ? (pv * sn + v * c) : (v * c - pv * sn);
        ((mid == 0) ? Qb : Kb)[oi] = f2bf(o);
      }
    }
  }
}

// ---------------- flash attention (causal), round 6 ----------------
// BM=64, fixed-max base-2 softmax (M=13): no per-iter max reduce, no alpha,
// no accO rescale, rs accumulated in regs (one reduction at the end).
// Ps overlaid on Qs (wave w's P rows = its own Q rows, qf already in regs).
// LDS = 40KB -> 4 blocks/CU. Balanced qt remap: CU gets {31-x,16+x,15-x,x}.
__global__ __launch_bounds__(256, 4) void attn_kernel(
    const short* __restrict__ Qb, const short* __restrict__ Kb,
    const short* __restrict__ Vb, short* __restrict__ Ob) {
  __shared__ __align__(16) short QPs[64 * 64];     // Q staging, then P tiles
  __shared__ __align__(16) short Ks[2][64 * 64];
  __shared__ __align__(16) short Vs[2][64 * 64];   // transposed: [dv][key]

  const int id = blockIdx.x;
  const int xx = id & 7;
  const int mm = (((id >> 3) & 3) + (id >> 8)) & 3;
  const int bh = id >> 5;
  const int qt = (mm == 0) ? (31 - xx) : (mm == 1) ? (16 + xx)
               : (mm == 2) ? (15 - xx) : xx;

  const int tid = threadIdx.x;
  const int wave = tid >> 6, lane = tid & 63;
  const int l15 = lane & 15, quad = lane >> 4;
  const int sr0 = tid >> 3, sc = tid & 7;

  const short* Qp = Qb + (size_t)bh * SEQ * DKH;
  const short* Kp = Kb + (size_t)bh * SEQ * DKH;
  const short* Vp = Vb + (size_t)bh * SEQ * DKH;

  uint4 kreg[2], vreg[2];
#pragma unroll
  for (int i = 0; i < 2; i++) {
    int r = sr0 + i * 32;
    kreg[i] = *reinterpret_cast<const uint4*>(Kp + (size_t)r * DKH + sc * 8);
    vreg[i] = *reinterpret_cast<const uint4*>(Vp + (size_t)r * DKH + sc * 8);
  }
#pragma unroll
  for (int i = 0; i < 2; i++) {
    int r = sr0 + i * 32;
    uint4 v = *reinterpret_cast<const uint4*>(Qp + (size_t)(qt * 64 + r) * DKH + sc * 8);
    *reinterpret_cast<uint4*>(&QPs[swz(r, sc)]) = v;
  }
#pragma unroll
  for (int i = 0; i < 2; i++) {
    int r = sr0 + i * 32;
    *reinterpret_cast<uint4*>(&Ks[0][swz(r, sc)]) = kreg[i];
    const short* vsp = reinterpret_cast<const short*>(&vreg[i]);
#pragma unroll
    for (int j = 0; j < 8; j++) {
      int dv = sc * 8 + j;
      Vs[0][dv * 64 + ((((r >> 3) ^ (dv & 7) ^ (dv >> 3)) & 7) << 3) + (r & 7)] = vsp[j];
    }
  }
  __syncthreads();
  short8 qf0, qf1;
  {
    int r = wave * 16 + l15;
    qf0 = *reinterpret_cast<const short8*>(&QPs[swz(r, quad)]);
    qf1 = *reinterpret_cast<const short8*>(&QPs[swz(r, 4 + quad)]);
  }

  f32x4 accO[4];
#pragma unroll
  for (int i = 0; i < 4; i++) accO[i] = (f32x4){0.f, 0.f, 0.f, 0.f};
  float rs[4] = {0.f, 0.f, 0.f, 0.f};

  const float SCL = 0.125f * 1.44269504089f;   // 1/sqrt(64) * log2(e)
  // fixed softmax shift: scores*SCL realistically within +-4; M=13 gives huge
  // headroom; softmax is shift-invariant so result is exact.
  const float FM = 13.0f;

  int buf = 0;
  for (int kt = 0; kt <= qt; kt++) {
    if (kt < qt) {
#pragma unroll
      for (int i = 0; i < 2; i++) {
        int r = (kt + 1) * 64 + sr0 + i * 32;
        kreg[i] = *reinterpret_cast<const uint4*>(Kp + (size_t)r * DKH + sc * 8);
        vreg[i] = *reinterpret_cast<const uint4*>(Vp + (size_t)r * DKH + sc * 8);
      }
    }

    // S = Q K^T
    f32x4 sa[4];
#pragma unroll
    for (int nb = 0; nb < 4; nb++) {
      sa[nb] = (f32x4){0.f, 0.f, 0.f, 0.f};
      int r = nb * 16 + l15;
      short8 kf0 = *reinterpret_cast<const short8*>(&Ks[buf][swz(r, quad)]);
      sa[nb] = __builtin_amdgcn_mfma_f32_16x16x32_bf16(qf0, kf0, sa[nb], 0, 0, 0);
      short8 kf1 = *reinterpret_cast<const short8*>(&Ks[buf][swz(r, 4 + quad)]);
      sa[nb] = __builtin_amdgcn_mfma_f32_16x16x32_bf16(qf1, kf1, sa[nb], 0, 0, 0);
    }

    // p = 2^(s*SCL - FM); mask on diagonal tile; accumulate rs in regs
    const bool diag = (kt == qt);
#pragma unroll
    for (int nb = 0; nb < 4; nb++)
#pragma unroll
      for (int reg = 0; reg < 4; reg++) {
        float p = exp2f(sa[nb][reg] * SCL - FM);
        if (diag && (nb * 16 + l15) > (wave * 16 + quad * 4 + reg)) p = 0.f;
        rs[reg] += p;
        int r = quad * 4 + reg, col = nb * 16 + l15;
        QPs[swz(wave * 16 + r, col >> 3) + (col & 7)] = f2bf(p);
      }

    // O += P V  (same-wave LDS write->read; no barrier needed)
    short8 pf0, pf1;
    {
      int r = wave * 16 + l15;
      pf0 = *reinterpret_cast<const short8*>(&QPs[swz(r, quad)]);
      pf1 = *reinterpret_cast<const short8*>(&QPs[swz(r, 4 + quad)]);
    }
#pragma unroll
    for (int db = 0; db < 4; db++) {
      int dv = db * 16 + l15;
      int fsw = (dv & 7) ^ (dv >> 3);
      short8 vf0 = *reinterpret_cast<const short8*>(
          &Vs[buf][dv * 64 + (((quad ^ fsw) & 7) << 3)]);
      accO[db] = __builtin_amdgcn_mfma_f32_16x16x32_bf16(pf0, vf0, accO[db], 0, 0, 0);
      short8 vf1 = *reinterpret_cast<const short8*>(
          &Vs[buf][dv * 64 + ((((quad + 4) ^ fsw) & 7) << 3)]);
      accO[db] = __builtin_amdgcn_mfma_f32_16x16x32_bf16(pf1, vf1, accO[db], 0, 0, 0);
    }

    if (kt < qt) {
      int nbuf = buf ^ 1;
#pragma unroll
      for (int i = 0; i < 2; i++) {
        int r = sr0 + i * 32;
        *reinterpret_cast<uint4*>(&Ks[nbuf][swz(r, sc)]) = kreg[i];
        const short* vsp = reinterpret_cast<const short*>(&vreg[i]);
#pragma unroll
        for (int j = 0; j < 8; j++) {
          int dv = sc * 8 + j;
          Vs[nbuf][dv * 64 + ((((r >> 3) ^ (dv & 7) ^ (dv >> 3)) & 7) << 3) + (r & 7)] = vsp[j];
        }
      }
      __syncthreads();
      buf = nbuf;
    }
  }

  // single end-of-loop row-sum reduction (16 lanes per row group)
  float lrow[4];
#pragma unroll
  for (int reg = 0; reg < 4; reg++) {
    float t = rs[reg];
#pragma unroll
    for (int off = 1; off < 16; off <<= 1) t += __shfl_xor(t, off);
    lrow[reg] = t;
  }

  // write (B,S,1024) bf16
  int b = bh >> 4, h = bh & 15;
#pragma unroll
  for (int db = 0; db < 4; db++)
#pragma unroll
    for (int reg = 0; reg < 4; reg++) {
      int s = qt * 64 + wave * 16 + quad * 4 + reg;
      int dv = db * 16 + l15;
      float o = accO[db][reg] / lrow[reg];
      Ob[((size_t)(b * SEQ + s)) * DMODEL + h * DKH + dv] = f2bf(o);
    }
}

// ---------------- output projection (bf16 inputs, fp32 output) ----------------
__global__ __launch_bounds__(256) void gemm_out_kernel(
    const short* __restrict__ X, const short* __restrict__ Wo, float* __restrict__ Out) {
  __shared__ __align__(16) short As[64 * 64];
  __shared__ __align__(16) short Bs[64 * 64];
  const int tm = blockIdx.x;   // 64
  const int tn = blockIdx.y;   // 16
  const int tid = threadIdx.x;
  const int wave = tid >> 6, lane = tid & 63;
  const int l15 = lane & 15, quad = lane >> 4;

  const short* Arow = X + (size_t)(tm * 64) * DMODEL;
  const short* Wrow = Wo + (size_t)(tn * 64) * DMODEL;

  f32x4 acc[4];
#pragma unroll
  for (int i = 0; i < 4; i++) acc[i] = (f32x4){0.f, 0.f, 0.f, 0.f};

  for (int kk = 0; kk < DMODEL; kk += 64) {
#pragma unroll
    for (int i = 0; i < 2; i++) {
      int g = tid + i * 256;
      int r = g >> 3, c = g & 7;
      uint4 va = *reinterpret_cast<const uint4*>(Arow + (size_t)r * DMODEL + kk + c * 8);
      *reinterpret_cast<uint4*>(&As[swz(r, c)]) = va;
      uint4 vb = *reinterpret_cast<const uint4*>(Wrow + (size_t)r * DMODEL + kk + c * 8);
      *reinterpret_cast<uint4*>(&Bs[swz(r, c)]) = vb;
    }
    __syncthreads();
    short8 af0, af1;
    {
      int r = wave * 16 + l15;
      af0 = *reinterpret_cast<const short8*>(&As[swz(r, quad)]);
      af1 = *reinterpret_cast<const short8*>(&As[swz(r, 4 + quad)]);
    }
#pragma unroll
    for (int nb = 0; nb < 4; nb++) {
      int r = nb * 16 + l15;
      short8 bf0 = *reinterpret_cast<const short8*>(&Bs[swz(r, quad)]);
      acc[nb] = __builtin_amdgcn_mfma_f32_16x16x32_bf16(af0, bf0, acc[nb], 0, 0, 0);
      short8 bf1 = *reinterpret_cast<const short8*>(&Bs[swz(r, 4 + quad)]);
      acc[nb] = __builtin_amdgcn_mfma_f32_16x16x32_bf16(af1, bf1, acc[nb], 0, 0, 0);
    }
    __syncthreads();
  }
#pragma unroll
  for (int nb = 0; nb < 4; nb++)
#pragma unroll
    for (int reg = 0; reg < 4; reg++) {
      int rg = tm * 64 + wave * 16 + quad * 4 + reg;
      int col = tn * 64 + nb * 16 + l15;
      Out[(size_t)rg * DMODEL + col] = acc[nb][reg];
    }
}

extern "C" void kernel_launch(void* const* d_in, const int* in_sizes, int n_in,
                              void* d_out, int out_size, void* d_ws, size_t ws_size,
                              hipStream_t stream) {
  (void)in_sizes; (void)n_in; (void)out_size; (void)ws_size;
  const float* X  = (const float*)d_in[0];
  const int*   tp = (const int*)d_in[1];
  const float* Wq = (const float*)d_in[2];
  const float* Wk = (const float*)d_in[3];
  const float* Wv = (const float*)d_in[4];
  const float* Wo = (const float*)d_in[5];
  float* Out = (float*)d_out;

  short* Qb  = (short*)d_ws;           // 4M shorts each
  short* Kb  = Qb + 4194304;
  short* Vb  = Kb + 4194304;
  short* Ab  = Vb + 4194304;
  short* Xb  = Ab + 4194304;           // 4M
  short* Wqb = Xb + 4194304;           // 1M each
  short* Wkb = Wqb + 1048576;
  short* Wvb = Wkb + 1048576;
  short* Wob = Wvb + 1048576;
  float* ct  = (float*)(Wob + 1048576);
  float* st  = ct + SEQ * 32;

  rope_table_kernel<<<dim3(256), dim3(256), 0, stream>>>(tp, ct, st);
  precast_kernel<<<dim3(4096), dim3(256), 0, stream>>>(X, Wq, Wk, Wv, Wo,
                                                       Xb, Wqb, Wkb, Wvb, Wob);
  gemm_qkv_kernel<<<dim3(64, 48), dim3(256), 0, stream>>>(Xb, Wqb, Wkb, Wvb,
                                                          Qb, Kb, Vb, ct, st);
  attn_kernel<<<dim3(1024), dim3(256), 0, stream>>>(Qb, Kb, Vb, Ab);
  gemm_out_kernel<<<dim3(64, 16), dim3(256), 0, stream>>>(Ab, Wob, Out);
}